// Round 5
// baseline (932.375 us; speedup 1.0000x reference)
//
#include <hip/hip_runtime.h>
#include <hip/hip_bf16.h>

// ---------------------------------------------------------------------------
// CombineMultiOutputModelWeightedConcat — LDS-free per-wave MFMA round.
// All GEMM stages: per-wave independent 64x64 tiles, A/B fragments loaded
// DIRECTLY from global (both operands k-contiguous; one frag = 8 halves/lane,
// lanes of a quad-group cover a full 64B line). Zero K-loop barriers, no LDS
// staging -> occupancy bound only by regs (64 AGPR acc + ~100 VGPR).
// ROWW (combine): gate weight y folded into A-fragments as fp16 scale
// (per-lane scalar), T-terms in epilogue -> single accumulator bank.
// BN folded into prescaled transposed fp16 weights (prep_w), as before.
// ---------------------------------------------------------------------------

typedef unsigned short u16;
typedef _Float16 f16x8 __attribute__((ext_vector_type(8)));
typedef float f32x4 __attribute__((ext_vector_type(4)));

#define B_ROWS 32768
#define EPS_BN 0.2f
#define BINV (1.0f / 32768.0f)

__device__ __forceinline__ float bf2f(u16 u) {
    union { unsigned int i; float f; } c;
    c.i = ((unsigned int)u) << 16;
    return c.f;
}
__device__ __forceinline__ u16 f2bf(float f) {
    union { float f; unsigned int i; } c;
    c.f = f;
    unsigned int x = c.i;
    return (u16)((x + 0x7FFFu + ((x >> 16) & 1u)) >> 16);
}
__device__ __forceinline__ float h2f(u16 u) {
    _Float16 h;
    __builtin_memcpy(&h, &u, 2);
    return (float)h;
}
__device__ __forceinline__ u16 f2h(float f) {
    _Float16 h = (_Float16)f;
    u16 u;
    __builtin_memcpy(&u, &h, 2);
    return u;
}
__device__ __forceinline__ float ldp(const void* p, long i, int flag) {
    return flag ? bf2f(((const u16*)p)[i]) : ((const float*)p)[i];
}

// --------------------------------------------------------------------------
__global__ void detect_dtype(const u16* __restrict__ x, int* __restrict__ flag) {
    const int lane = threadIdx.x;  // 64 threads
    const u16 v = x[2 * lane];
    const int e = (v >> 7) & 0xFF;
    const bool plausible = (e >= 110 && e <= 140);
    const unsigned long long m = __ballot(plausible);
    if (lane == 0) *flag = (__popcll(m) >= 58) ? 1 : 0;
}

struct PTab { const void* p[20]; int n[20]; int off[20]; };

__global__ void convert_params(PTab t, float* __restrict__ dst,
                               const int* __restrict__ flag) {
    const int ti = blockIdx.y;
    const int n = t.n[ti];
    float* o = dst + t.off[ti];
    const int isbf = *flag;
    for (int i = blockIdx.x * 256 + threadIdx.x; i < n; i += gridDim.x * 256)
        o[i] = ldp(t.p[ti], i, isbf);
}

// ---------------------------------------------------------------------------
// prep_w: Wt[inst][n][k] = f16(s_k * W[k][n]);  T0/T1[n] = sum_{k<,>=khalf}
// t_k*W[k][n];  biasP = bias;  bsum = bias+T0+T1.  s,t from producer stats.
// grid = (N, numInst), 256 threads.
// ---------------------------------------------------------------------------
__global__ __launch_bounds__(256) void prep_w(
    const void* __restrict__ W, long wstride,
    const void* __restrict__ bias, long bstride,
    const float* __restrict__ psum, const float* __restrict__ psq, int pstride,
    const void* __restrict__ pg, const void* __restrict__ pbe, int gmask,
    const int* __restrict__ dtflag,
    u16* __restrict__ Wt, long wtstride,
    float* __restrict__ biasP, float* __restrict__ T0o,
    float* __restrict__ T1o, float* __restrict__ bsum, long bost,
    int K, int khalf)
{
    const int tid = threadIdx.x;
    const int n = blockIdx.x;
    const int N = gridDim.x;
    const int inst = blockIdx.y;
    const int flag = *dtflag;
    __shared__ float sn[512], tn[512];
    __shared__ float r0[4], r1[4];

    for (int i = tid; i < K; i += 256) {
        float s = 1.f, t = 0.f;
        if (psum) {
            float m = psum[(long)pstride * inst + i] * BINV;
            float v = psq[(long)pstride * inst + i] * BINV - m * m;
            float g = ldp(pg, i & gmask, flag);
            float b = ldp(pbe, i & gmask, flag);
            s = g * rsqrtf(v + EPS_BN);
            t = b - m * s;
        }
        sn[i] = s; tn[i] = t;
    }
    __syncthreads();
    float p0 = 0.f, p1 = 0.f;
    for (int k = tid; k < K; k += 256) {
        float wv = ldp(W, wstride * inst + (long)k * N + n, flag);
        Wt[wtstride * inst + (long)n * K + k] = f2h(sn[k] * wv);
        float tw = tn[k] * wv;
        if (k < khalf) p0 += tw; else p1 += tw;
    }
#pragma unroll
    for (int off = 32; off; off >>= 1) {
        p0 += __shfl_xor(p0, off);
        p1 += __shfl_xor(p1, off);
    }
    const int lane = tid & 63, wid = tid >> 6;
    if (lane == 0) { r0[wid] = p0; r1[wid] = p1; }
    __syncthreads();
    if (tid == 0) {
        float t0 = r0[0] + r0[1] + r0[2] + r0[3];
        float t1 = r1[0] + r1[1] + r1[2] + r1[3];
        float bp = ldp(bias, bstride * inst + n, flag);
        long o = bost * inst + n;
        biasP[o] = bp; T0o[o] = t0; T1o[o] = t1; bsum[o] = bp + t0 + t1;
    }
}

// ---------------------------------------------------------------------------
// LDS-free MFMA GEMM. 256 threads = 4 waves arranged WM x WN; each wave owns
// a 64x64 output tile (rows rowBase.., cols n0..). Fragments loaded straight
// from global: lane reads [row][kk + quad*8 .. +7] (16B, quads cover a full
// 64B line). No barriers in the K-loop. Epilogue: bias/gate + relu + fp16
// store + per-block column sum/sumsq reduction (one barrier) + atomics.
// ---------------------------------------------------------------------------
template <bool XSTAGE, bool ROWW, int WM, int WN, int K>
__global__ __launch_bounds__(256, 2) void gemm_mfma(
    const void* __restrict__ X, const void* __restrict__ X2,
    long xstride, int ximask, int ldx, int ksplit, long ksecond,
    const int* __restrict__ dtflag,
    const u16* __restrict__ Wt, long wtstride,
    const float* __restrict__ biasP, const float* __restrict__ T0,
    const float* __restrict__ T1, const float* __restrict__ bsum, int bN,
    u16* __restrict__ Out, long ostride, int ldout,
    float* __restrict__ gsum, float* __restrict__ gsq, int sstride,
    const float* __restrict__ Y0v)
{
    const int tid = threadIdx.x;
    const int lane = tid & 63;
    const int wid = tid >> 6;
    const int wm = wid / WN, wn = wid % WN;
    const int inst = blockIdx.z;
    const int rowBase = blockIdx.x * (64 * WM) + wm * 64;
    const int nBase = blockIdx.y * (64 * WN);
    const int n0 = nBase + wn * 64;
    const int fm = lane & 15, quad = lane >> 4;

    __shared__ float redS[WM * WN][64];
    __shared__ float redQ[WM * WN][64];

    const bool xf32 = XSTAGE && (*dtflag == 0);
    const char* xb;
    if (XSTAGE) xb = (const char*)(inst == 0 ? X : X2);
    else        xb = (const char*)X + 2l * xstride * (inst & ximask);
    const u16* wtp = Wt + wtstride * inst;
    u16* op = Out + ostride * inst;

    f32x4 acc[4][4];
#pragma unroll
    for (int i = 0; i < 4; ++i)
#pragma unroll
        for (int j = 0; j < 4; ++j) acc[i][j] = (f32x4){0.f, 0.f, 0.f, 0.f};

    _Float16 ysc[2][4];   // [sel][mi] gate weight for this lane's A rows
    if constexpr (ROWW) {
        const float* yp = Y0v + (long)inst * B_ROWS;
#pragma unroll
        for (int mi = 0; mi < 4; ++mi) {
            const float y = yp[rowBase + mi * 16 + fm];
            ysc[0][mi] = (_Float16)y;
            ysc[1][mi] = (_Float16)(1.f - y);
        }
    }

#pragma unroll 4
    for (int kc = 0; kc < K / 32; ++kc) {
        const int kk = kc * 32;
        f16x8 af[4], bf[4];

        if (XSTAGE) {
            if (xf32) {
                const float* xs = (const float*)xb;
#pragma unroll
                for (int mi = 0; mi < 4; ++mi) {
                    const float* g = xs + (long)(rowBase + mi * 16 + fm) * ldx + kk + quad * 8;
                    const float4 u = *(const float4*)g;
                    const float4 u2 = *(const float4*)(g + 4);
                    f16x8 h;
                    h[0] = (_Float16)u.x;  h[1] = (_Float16)u.y;
                    h[2] = (_Float16)u.z;  h[3] = (_Float16)u.w;
                    h[4] = (_Float16)u2.x; h[5] = (_Float16)u2.y;
                    h[6] = (_Float16)u2.z; h[7] = (_Float16)u2.w;
                    af[mi] = h;
                }
            } else {
                const u16* xs = (const u16*)xb;
#pragma unroll
                for (int mi = 0; mi < 4; ++mi) {
                    const uint4 v = *(const uint4*)(xs + (long)(rowBase + mi * 16 + fm) * ldx + kk + quad * 8);
                    const u16* pv = (const u16*)&v;
                    f16x8 h;
#pragma unroll
                    for (int j = 0; j < 8; ++j) h[j] = (_Float16)bf2f(pv[j]);
                    af[mi] = h;
                }
            }
        } else {
            const u16* xs = (const u16*)xb;
            int kkr = kk;
            if (kk >= ksplit) { xs += ksecond; kkr -= ksplit; }
#pragma unroll
            for (int mi = 0; mi < 4; ++mi)
                af[mi] = *(const f16x8*)(xs + (long)(rowBase + mi * 16 + fm) * ldx + kkr + quad * 8);
        }

        if constexpr (ROWW) {
            const int sel = (kk < ksplit) ? 0 : 1;
#pragma unroll
            for (int mi = 0; mi < 4; ++mi) {
                const _Float16 yh = ysc[sel][mi];
#pragma unroll
                for (int j = 0; j < 8; ++j) af[mi][j] *= yh;
            }
        }

#pragma unroll
        for (int ni = 0; ni < 4; ++ni)
            bf[ni] = *(const f16x8*)(wtp + (long)(n0 + ni * 16 + fm) * K + kk + quad * 8);

#pragma unroll
        for (int mi = 0; mi < 4; ++mi)
#pragma unroll
            for (int ni = 0; ni < 4; ++ni)
                acc[mi][ni] = __builtin_amdgcn_mfma_f32_16x16x32_f16(
                    af[mi], bf[ni], acc[mi][ni], 0, 0, 0);
    }

    // ---- epilogue ----
    float yv[16];
    if constexpr (ROWW) {
        const float* yp = Y0v + (long)inst * B_ROWS;
#pragma unroll
        for (int mi = 0; mi < 4; ++mi)
#pragma unroll
            for (int r = 0; r < 4; ++r)
                yv[mi * 4 + r] = yp[rowBase + mi * 16 + quad * 4 + r];
    }

#pragma unroll
    for (int ni = 0; ni < 4; ++ni) {
        const int nc = ni * 16 + fm;
        const int n = n0 + nc;
        float bS = 0.f, bP = 0.f, t0v = 0.f, t1v = 0.f;
        if constexpr (ROWW) {
            bP = biasP[(long)inst * bN + n];
            t0v = T0[(long)inst * bN + n];
            t1v = T1[(long)inst * bN + n];
        } else {
            bS = bsum[(long)inst * bN + n];
        }
        float s = 0.f, qq = 0.f;
#pragma unroll
        for (int mi = 0; mi < 4; ++mi) {
            const int rbase = rowBase + mi * 16 + quad * 4;
#pragma unroll
            for (int r = 0; r < 4; ++r) {
                float v;
                if constexpr (ROWW) {
                    const float y = yv[mi * 4 + r];
                    v = acc[mi][ni][r] + y * t0v + (1.f - y) * t1v + bP;
                } else {
                    v = acc[mi][ni][r] + bS;
                }
                v = fmaxf(v, 0.f);
                s += v; qq += v * v;
                op[(long)(rbase + r) * ldout + n] = f2h(v);
            }
        }
        s += __shfl_xor(s, 16);  s += __shfl_xor(s, 32);
        qq += __shfl_xor(qq, 16); qq += __shfl_xor(qq, 32);
        if (quad == 0) { redS[wid][nc] = s; redQ[wid][nc] = qq; }
    }
    __syncthreads();
    if (tid < WN * 64) {
        const int wnc = tid >> 6, within = tid & 63;
        float s = 0.f, q = 0.f;
#pragma unroll
        for (int w = 0; w < WM; ++w) {
            s += redS[w * WN + wnc][within];
            q += redQ[w * WN + wnc][within];
        }
        atomicAdd(&gsum[(long)inst * sstride + nBase + tid], s);
        atomicAdd(&gsq [(long)inst * sstride + nBase + tid], q);
    }
}

// ---------------------------------------------------------------------------
__global__ __launch_bounds__(256) void gate_kernel(
    const u16* __restrict__ zc,
    const float* __restrict__ stFs, const float* __restrict__ stFq,
    const float* __restrict__ g4, const float* __restrict__ be4,
    const float* __restrict__ Wy, const float* __restrict__ by,
    float* __restrict__ Y0)
{
    const int lane = threadIdx.x & 63;
    const int wid = threadIdx.x >> 6;
    const int k = blockIdx.y;
    const int row = blockIdx.x * 4 + wid;

    const float m = stFs[k * 64 + lane] * BINV;
    const float v = stFq[k * 64 + lane] * BINV - m * m;
    const float s = g4[lane] * rsqrtf(v + EPS_BN);
    const float t = be4[lane] - m * s;
    const float x = h2f(zc[((long)k * B_ROWS + row) * 64 + lane]) * s + t;

    float p0 = x * Wy[k * 128 + lane * 2 + 0];
    float p1 = x * Wy[k * 128 + lane * 2 + 1];
#pragma unroll
    for (int off = 32; off; off >>= 1) {
        p0 += __shfl_xor(p0, off);
        p1 += __shfl_xor(p1, off);
    }
    if (lane == 0) {
        const float l0 = p0 + by[k * 2 + 0];
        const float l1 = p1 + by[k * 2 + 1];
        Y0[(long)k * B_ROWS + row] = 1.f / (1.f + __expf(l1 - l0));
    }
}

// ---------------------------------------------------------------------------
__global__ __launch_bounds__(256) void heads_kernel(
    const u16* __restrict__ zxc,
    const float* __restrict__ stHs, const float* __restrict__ stHq,
    const float* __restrict__ g1, const float* __restrict__ be1,
    const float* __restrict__ Wo1, const float* __restrict__ bo1,
    const float* __restrict__ Wo2, const float* __restrict__ bo2,
    const float* __restrict__ Wo3, const float* __restrict__ bo3,
    const float* __restrict__ Wo4, const float* __restrict__ bo4,
    void* __restrict__ out, const int* __restrict__ dtflag)
{
    const int lane = threadIdx.x & 63;
    const int wid = threadIdx.x >> 6;
    const int k = blockIdx.y;
    const int row = blockIdx.x * 4 + wid;
    const int c0 = lane * 4;

    const ushort4 q = *(const ushort4*)(zxc + ((long)k * B_ROWS + row) * 256 + c0);
    float x[4] = {h2f(q.x), h2f(q.y), h2f(q.z), h2f(q.w)};
#pragma unroll
    for (int j = 0; j < 4; j++) {
        const int c = c0 + j;
        const float m = stHs[k * 256 + c] * BINV;
        const float v = stHq[k * 256 + c] * BINV - m * m;
        const float s = g1[c] * rsqrtf(v + EPS_BN);
        x[j] = x[j] * s + (be1[c] - m * s);
    }

    const float* Wo; const float* bo; int nk; long obase;
    if (k == 0)      { Wo = Wo1; bo = bo1; nk = 3; obase = 0; }
    else if (k == 1) { Wo = Wo2; bo = bo2; nk = 3; obase = (long)3 * B_ROWS; }
    else if (k == 2) { Wo = Wo3; bo = bo3; nk = 6; obase = (long)6 * B_ROWS; }
    else             { Wo = Wo4; bo = bo4; nk = 4; obase = (long)12 * B_ROWS; }

    float l[6];
#pragma unroll
    for (int j = 0; j < 6; j++) l[j] = 0.f;
#pragma unroll
    for (int j = 0; j < 6; j++) {
        if (j < nk) {
            float p = 0.f;
#pragma unroll
            for (int i = 0; i < 4; i++) p += x[i] * Wo[(c0 + i) * nk + j];
            l[j] = p;
        }
    }
#pragma unroll
    for (int off = 32; off; off >>= 1) {
#pragma unroll
        for (int j = 0; j < 6; j++) l[j] += __shfl_xor(l[j], off);
    }

    if (lane == 0) {
        float mx = -1e30f;
#pragma unroll
        for (int j = 0; j < 6; j++)
            if (j < nk) { l[j] += bo[j]; mx = fmaxf(mx, l[j]); }
        float e[6];
        float se = 0.f;
#pragma unroll
        for (int j = 0; j < 6; j++)
            if (j < nk) { e[j] = __expf(l[j] - mx); se += e[j]; }
        const float inv = 1.f / se;
        if (*dtflag) {
            u16* ob = (u16*)out;
#pragma unroll
            for (int j = 0; j < 6; j++)
                if (j < nk) ob[obase + (long)row * nk + j] = f2bf(e[j] * inv);
        } else {
            float* of = (float*)out;
#pragma unroll
            for (int j = 0; j < 6; j++)
                if (j < nk) of[obase + (long)row * nk + j] = e[j] * inv;
        }
    }
}

__global__ void fill_sentinel(u16* out, int n) {
    int i = blockIdx.x * 256 + threadIdx.x;
    if (i < n) out[i] = 0x3E80;
}

// ---------------------------------------------------------------------------
extern "C" void kernel_launch(void* const* d_in, const int* in_sizes, int n_in,
                              void* d_out, int out_size, void* d_ws, size_t ws_size,
                              hipStream_t stream)
{
    const long B = B_ROWS;
    char* ws = (char*)d_ws;
    const size_t MB = 1024 * 1024;

    // Lifetime-aliased activation layout (fp16)
    u16* z1  = (u16*)(ws);                      // [2][B][256]
    u16* z2  = (u16*)(ws + 32 * MB);            // [2][B][256]
    u16* za  = (u16*)(ws);                      // [4][B][128]
    u16* zbb = (u16*)(ws + 32 * MB);            // [4][B][64]
    u16* zc  = (u16*)(ws + 48 * MB);            // [4][B][64]
    u16* zxc = (u16*)(ws);                      // [4][B][256]
    u16* zb  = (u16*)(ws + 64 * MB);            // [k][s][B][256]
    float* Y0 = (float*)(ws + 192 * MB);                   // 512 KB
    float* stats = (float*)(ws + 192 * MB + 512 * 1024);   // 40 KB
    int* dtflag = (int*)(ws + 192 * MB + 576 * 1024);
    float* Pst = (float*)(ws + 192 * MB + 640 * 1024);     // small fp32 params

    // Wt region (fp16, prescaled+transposed weights)
    u16* WtA = (u16*)(ws + 193 * MB);                 // [256][512]
    u16* WtB = WtA + 131072;                          // [2][256][256]
    u16* WtC = WtB + 131072;                          // [8][256][256]
    u16* WtD = WtC + 524288;                          // [4][128][512]
    u16* WtH = WtD + 262144;                          // [4][256][512]
    u16* WtE = WtH + 524288;                          // [4][64][128]
    u16* WtF = WtE + 32768;                           // [4][64][64]
    float* biasArea = (float*)(ws + 197 * MB);
    float* bA = biasArea;        // 2048 (4 arrays x 2 inst x 256)
    float* bB = bA + 2048;       // 2048
    float* bC = bB + 2048;       // 8192 (4 arrays x 8 x 256)
    float* bD = bC + 8192;       // 2048 (4 x 4 x 128)
    float* bH = bD + 2048;       // 4096 (4 x 4 x 256)
    float* bE = bH + 4096;       // 1024 (4 x 4 x 64)
    float* bF = bE + 1024;       // 1024

    // fp32 param staging (gate/heads consumers)
    const int cIdx[20] = {6,7,10,11,12,13,20,21,22,23,24,25,28,29,30,31,32,33,34,35};
    PTab tab;
    int mapOff[36];
    int acc = 0;
    for (int i = 0; i < 20; i++) {
        tab.p[i] = d_in[cIdx[i]];
        tab.n[i] = in_sizes[cIdx[i]];
        tab.off[i] = acc;
        mapOff[cIdx[i]] = acc;
        acc += in_sizes[cIdx[i]];
    }
    const size_t need = 197 * MB + 20480 * 4 + 4096;
    if (need > ws_size || (size_t)acc * 4 > 384 * 1024) {
        fill_sentinel<<<(out_size + 255) / 256, 256, 0, stream>>>((u16*)d_out, out_size);
        return;
    }
    auto PF = [&](int idx) { return Pst + mapOff[idx]; };

    float* stAs = stats;        float* stAq = stAs + 512;   // [2][256]
    float* stBs = stAq + 512;   float* stBq = stBs + 512;   // [2][256]
    float* stCs = stBq + 512;   float* stCq = stCs + 2048;  // [k][s][256]
    float* stDs = stCq + 2048;  float* stDq = stDs + 512;   // [4][128]
    float* stEs = stDq + 512;   float* stEq = stEs + 256;   // [4][64]
    float* stFs = stEq + 256;   float* stFq = stFs + 256;   // [4][64]
    float* stHs = stFq + 256;   float* stHq = stHs + 1024;  // [4][256]

    hipMemsetAsync(stats, 0, 10240 * 4, stream);
    detect_dtype<<<1, 64, 0, stream>>>((const u16*)d_in[0], dtflag);
    convert_params<<<dim3(32, 20), 256, 0, stream>>>(tab, Pst, dtflag);

    const dim3 blk(256);
    const int BIGK = 1 << 29;  // "never split"

    // ---- Stage A: trunk L1 (dual-dtype X, no norm) -----------------------
    prep_w<<<dim3(256, 2), blk, 0, stream>>>(
        d_in[2], 0, d_in[3], 0, nullptr, nullptr, 0, nullptr, nullptr, 0,
        dtflag, WtA, 0, bA, bA + 512, bA + 1024, bA + 1536, 256, 512, 512);
    gemm_mfma<true, false, 1, 4, 512><<<dim3(512, 1, 2), blk, 0, stream>>>(
        d_in[0], d_in[1], 0, 0, 512, BIGK, 0, dtflag, WtA, 0,
        bA, bA + 512, bA + 1024, bA + 1536, 256,
        z1, B * 256, 256, stAs, stAq, 256, nullptr);

    // ---- Stage B: trunk L2 (norm stA + g1/be1 folded into WtB) -----------
    prep_w<<<dim3(256, 2), blk, 0, stream>>>(
        d_in[4], 0, d_in[5], 0, stAs, stAq, 256, d_in[6], d_in[7], 255,
        dtflag, WtB, 65536, bB, bB + 512, bB + 1024, bB + 1536, 256, 256, 256);
    gemm_mfma<false, false, 1, 4, 256><<<dim3(512, 1, 2), blk, 0, stream>>>(
        z1, nullptr, B * 256, 3, 256, BIGK, 0, dtflag, WtB, 65536,
        bB, bB + 512, bB + 1024, bB + 1536, 256,
        z2, B * 256, 256, stBs, stBq, 256, nullptr);

    // ---- Stage C: 8 branch projections (norm stB + g2/be2) ---------------
    for (int s = 0; s < 2; s++) {
        prep_w<<<dim3(256, 4), blk, 0, stream>>>(
            d_in[s ? 16 : 14], 65536, d_in[s ? 17 : 15], 256,
            stBs + s * 256, stBq + s * 256, 0, d_in[8], d_in[9], 255,
            dtflag, WtC + s * 65536, 131072,
            bC + s * 256, bC + 2048 + s * 256, bC + 4096 + s * 256,
            bC + 6144 + s * 256, 512, 256, 256);
    }
    gemm_mfma<false, false, 1, 4, 256><<<dim3(512, 1, 8), blk, 0, stream>>>(
        z2, nullptr, B * 256, 1, 256, BIGK, 0, dtflag, WtC, 65536,
        bC, bC + 2048, bC + 4096, bC + 6144, 256,
        zb, B * 256, 256, stCs, stCq, 256, nullptr);

    // ---- Stage D prep+gemm, H prep (stC available) -----------------------
    prep_w<<<dim3(128, 4), blk, 0, stream>>>(
        d_in[18], 65536, d_in[19], 128, stCs, stCq, 512, d_in[6], d_in[7], 255,
        dtflag, WtD, 65536, bD, bD + 512, bD + 1024, bD + 1536, 128, 512, 512);
    prep_w<<<dim3(256, 4), blk, 0, stream>>>(
        d_in[26], 131072, d_in[27], 256, stCs, stCq, 512, d_in[6], d_in[7], 255,
        dtflag, WtH, 131072, bH, bH + 1024, bH + 2048, bH + 3072, 256, 512, 256);
    gemm_mfma<false, false, 2, 2, 512><<<dim3(256, 1, 4), blk, 0, stream>>>(
        zb, nullptr, 2 * B * 256, 3, 256, 256, B * 256, dtflag, WtD, 65536,
        bD, bD + 512, bD + 1024, bD + 1536, 128,
        za, B * 128, 128, stDs, stDq, 128, nullptr);

    // ---- Stage E: gating layer b (norm stD + g3/be3) ---------------------
    prep_w<<<dim3(64, 4), blk, 0, stream>>>(
        d_in[20], 8192, d_in[21], 64, stDs, stDq, 128, d_in[10], d_in[11], 127,
        dtflag, WtE, 8192, bE, bE + 256, bE + 512, bE + 768, 64, 128, 128);
    gemm_mfma<false, false, 4, 1, 128><<<dim3(128, 1, 4), blk, 0, stream>>>(
        za, nullptr, B * 128, 3, 128, BIGK, 0, dtflag, WtE, 8192,
        bE, bE + 256, bE + 512, bE + 768, 64,
        zbb, B * 64, 64, stEs, stEq, 64, nullptr);

    // ---- Stage F: gating layer c (norm stE + g4/be4) ---------------------
    prep_w<<<dim3(64, 4), blk, 0, stream>>>(
        d_in[22], 4096, d_in[23], 64, stEs, stEq, 64, d_in[12], d_in[13], 63,
        dtflag, WtF, 4096, bF, bF + 256, bF + 512, bF + 768, 64, 64, 64);
    gemm_mfma<false, false, 4, 1, 64><<<dim3(128, 1, 4), blk, 0, stream>>>(
        zbb, nullptr, B * 64, 3, 64, BIGK, 0, dtflag, WtF, 4096,
        bF, bF + 256, bF + 512, bF + 768, 64,
        zc, B * 64, 64, stFs, stFq, 64, nullptr);

    // ---- Gate ------------------------------------------------------------
    gate_kernel<<<dim3(B_ROWS / 4, 4), blk, 0, stream>>>(
        zc, stFs, stFq, PF(12), PF(13), PF(24), PF(25), Y0);

    // ---- Stage H: combine, gate weight folded into A-fragments -----------
    gemm_mfma<false, true, 1, 4, 512><<<dim3(512, 1, 4), blk, 0, stream>>>(
        zb, nullptr, 2 * B * 256, 3, 256, 256, B * 256, dtflag, WtH, 131072,
        bH, bH + 1024, bH + 2048, bH + 3072, 256,
        zxc, B * 256, 256, stHs, stHq, 256, Y0);

    // ---- Output heads ----------------------------------------------------
    heads_kernel<<<dim3(B_ROWS / 4, 4), blk, 0, stream>>>(
        zxc, stHs, stHq, PF(6), PF(7), PF(28), PF(29), PF(30), PF(31),
        PF(32), PF(33), PF(34), PF(35), d_out, dtflag);
}

// Round 6
// 693.189 us; speedup vs baseline: 1.3451x; 1.3451x over previous
//
#include <hip/hip_runtime.h>
#include <hip/hip_bf16.h>

// ---------------------------------------------------------------------------
// CombineMultiOutputModelWeightedConcat — m97-style LDS-staged MFMA round.
// 128x128 (or 256x64) block tile, BK=64, single-buffered LDS staged with
// global_load_lds(16B) (XOR-swizzled k-contiguous layout, ds_read_b128
// fragments, 0 bank conflicts), 4 waves x 64x64 tiles, 64 AGPR acc.
// ROWW (combine): gate weight scales A-fragments in-register (single bank).
// BN folded into prescaled transposed fp16 weights (prep_w) as before.
// Stage A converts fp32/bf16 -> fp16 in a VALU staging path.
// ---------------------------------------------------------------------------

typedef unsigned short u16;
typedef _Float16 f16x8 __attribute__((ext_vector_type(8)));
typedef float f32x4 __attribute__((ext_vector_type(4)));

#define B_ROWS 32768
#define EPS_BN 0.2f
#define BINV (1.0f / 32768.0f)

__device__ __forceinline__ float bf2f(u16 u) {
    union { unsigned int i; float f; } c;
    c.i = ((unsigned int)u) << 16;
    return c.f;
}
__device__ __forceinline__ u16 f2bf(float f) {
    union { float f; unsigned int i; } c;
    c.f = f;
    unsigned int x = c.i;
    return (u16)((x + 0x7FFFu + ((x >> 16) & 1u)) >> 16);
}
__device__ __forceinline__ float h2f(u16 u) {
    _Float16 h;
    __builtin_memcpy(&h, &u, 2);
    return (float)h;
}
__device__ __forceinline__ u16 f2h(float f) {
    _Float16 h = (_Float16)f;
    u16 u;
    __builtin_memcpy(&u, &h, 2);
    return u;
}
__device__ __forceinline__ float ldp(const void* p, long i, int flag) {
    return flag ? bf2f(((const u16*)p)[i]) : ((const float*)p)[i];
}
// async global->LDS, 16B per lane; lds base wave-uniform, lane i lands at +16i
__device__ __forceinline__ void gload16(const u16* gp, u16* lp) {
    __builtin_amdgcn_global_load_lds(
        (const __attribute__((address_space(1))) unsigned int*)gp,
        (__attribute__((address_space(3))) unsigned int*)lp, 16, 0, 0);
}

// --------------------------------------------------------------------------
__global__ void detect_dtype(const u16* __restrict__ x, int* __restrict__ flag) {
    const int lane = threadIdx.x;  // 64 threads
    const u16 v = x[2 * lane];
    const int e = (v >> 7) & 0xFF;
    const bool plausible = (e >= 110 && e <= 140);
    const unsigned long long m = __ballot(plausible);
    if (lane == 0) *flag = (__popcll(m) >= 58) ? 1 : 0;
}

struct PTab { const void* p[20]; int n[20]; int off[20]; };

__global__ void convert_params(PTab t, float* __restrict__ dst,
                               const int* __restrict__ flag) {
    const int ti = blockIdx.y;
    const int n = t.n[ti];
    float* o = dst + t.off[ti];
    const int isbf = *flag;
    for (int i = blockIdx.x * 256 + threadIdx.x; i < n; i += gridDim.x * 256)
        o[i] = ldp(t.p[ti], i, isbf);
}

// ---------------------------------------------------------------------------
// prep_w: Wt[inst][n][k] = f16(s_k * W[k][n]);  T0/T1[n] = sum_{k<,>=khalf}
// t_k*W[k][n];  biasP = bias;  bsum = bias+T0+T1.
// ---------------------------------------------------------------------------
__global__ __launch_bounds__(256) void prep_w(
    const void* __restrict__ W, long wstride,
    const void* __restrict__ bias, long bstride,
    const float* __restrict__ psum, const float* __restrict__ psq, int pstride,
    const void* __restrict__ pg, const void* __restrict__ pbe, int gmask,
    const int* __restrict__ dtflag,
    u16* __restrict__ Wt, long wtstride,
    float* __restrict__ biasP, float* __restrict__ T0o,
    float* __restrict__ T1o, float* __restrict__ bsum, long bost,
    int K, int khalf)
{
    const int tid = threadIdx.x;
    const int n = blockIdx.x;
    const int N = gridDim.x;
    const int inst = blockIdx.y;
    const int flag = *dtflag;
    __shared__ float sn[512], tn[512];
    __shared__ float r0[4], r1[4];

    for (int i = tid; i < K; i += 256) {
        float s = 1.f, t = 0.f;
        if (psum) {
            float m = psum[(long)pstride * inst + i] * BINV;
            float v = psq[(long)pstride * inst + i] * BINV - m * m;
            float g = ldp(pg, i & gmask, flag);
            float b = ldp(pbe, i & gmask, flag);
            s = g * rsqrtf(v + EPS_BN);
            t = b - m * s;
        }
        sn[i] = s; tn[i] = t;
    }
    __syncthreads();
    float p0 = 0.f, p1 = 0.f;
    for (int k = tid; k < K; k += 256) {
        float wv = ldp(W, wstride * inst + (long)k * N + n, flag);
        Wt[wtstride * inst + (long)n * K + k] = f2h(sn[k] * wv);
        float tw = tn[k] * wv;
        if (k < khalf) p0 += tw; else p1 += tw;
    }
#pragma unroll
    for (int off = 32; off; off >>= 1) {
        p0 += __shfl_xor(p0, off);
        p1 += __shfl_xor(p1, off);
    }
    const int lane = tid & 63, wid = tid >> 6;
    if (lane == 0) { r0[wid] = p0; r1[wid] = p1; }
    __syncthreads();
    if (tid == 0) {
        float t0 = r0[0] + r0[1] + r0[2] + r0[3];
        float t1 = r1[0] + r1[1] + r1[2] + r1[3];
        float bp = ldp(bias, bstride * inst + n, flag);
        long o = bost * inst + n;
        biasP[o] = bp; T0o[o] = t0; T1o[o] = t1; bsum[o] = bp + t0 + t1;
    }
}

// ---------------------------------------------------------------------------
// LDS-staged MFMA GEMM. Block tile (WM*64) x (WN*64), BK=64, 256 threads =
// 4 waves arranged WM x WN (each wave 64x64, 4x4 of 16x16x32, 64 AGPR).
// LDS layout: tile[r][c] (c = 16B k-chunk) stores global chunk c ^ (r&7);
// staged by global_load_lds (8 rows / inst), read back as ds_read_b128.
// ROWW: per-row gate weight scales A-fragments in-register.
// Epilogue: bias/gate + relu + fp16 store + column sum/sumsq atomics.
// ---------------------------------------------------------------------------
template <bool XSTAGE, bool ROWW, int WM, int WN, int K>
__global__ __launch_bounds__(256, 3) void gemm_mfma(
    const void* __restrict__ X, const void* __restrict__ X2,
    long xstride, int ximask, int ldx, int ksplit, long ksecond,
    const int* __restrict__ dtflag,
    const u16* __restrict__ Wt, long wtstride,
    const float* __restrict__ biasP, const float* __restrict__ T0,
    const float* __restrict__ T1, const float* __restrict__ bsum, int bN,
    u16* __restrict__ Out, long ostride, int ldout,
    float* __restrict__ gsum, float* __restrict__ gsq, int sstride,
    const float* __restrict__ Y0v)
{
    const int tid = threadIdx.x;
    const int lane = tid & 63;
    const int wid = tid >> 6;
    const int wm = wid / WN, wn = wid % WN;
    const int inst = blockIdx.z;
    const int rowB = blockIdx.x * (64 * WM);
    const int nBase = blockIdx.y * (64 * WN);
    const int n0 = nBase + wn * 64;
    const int fm = lane & 15, quad = lane >> 4;
    const int rloc = lane >> 3;            // staging: row within 8-row group
    const int cg = (lane & 7) ^ rloc;      // staging: swizzled global chunk

    __shared__ __align__(16) u16 As[WM * 4096];   // [WM*64][64] halves
    __shared__ __align__(16) u16 Bs[WN * 4096];   // [WN*64][64] halves
    __shared__ float redS[4][64];
    __shared__ float redQ[4][64];

    const bool xf32 = XSTAGE && (*dtflag == 0);
    const char* xb;
    if (XSTAGE) xb = (const char*)(inst == 0 ? X : X2);
    else        xb = (const char*)X + 2l * xstride * (inst & ximask);
    const u16* wtp = Wt + wtstride * inst;
    u16* op = Out + ostride * inst;

    f32x4 acc[4][4];
#pragma unroll
    for (int i = 0; i < 4; ++i)
#pragma unroll
        for (int j = 0; j < 4; ++j) acc[i][j] = (f32x4){0.f, 0.f, 0.f, 0.f};

    _Float16 ysc[2][4];
    if constexpr (ROWW) {
        const float* yp = Y0v + (long)inst * B_ROWS;
#pragma unroll
        for (int mi = 0; mi < 4; ++mi) {
            const float y = yp[rowB + wm * 64 + mi * 16 + fm];
            ysc[0][mi] = (_Float16)y;
            ysc[1][mi] = (_Float16)(1.f - y);
        }
    }

    for (int kt = 0; kt < K / 64; ++kt) {
        const int kk = kt * 64;
        __syncthreads();
        // ---- stage A tile ----
        if constexpr (XSTAGE) {
            // VALU convert path (fp32 or bf16 -> fp16), same swizzled layout
#pragma unroll
            for (int p = 0; p < WM * 2; ++p) {
                const int s = p * 256 + tid;       // chunk id
                const int m = s >> 3, c = s & 7;
                const int g = c ^ (m & 7);
                f16x8 h;
                if (xf32) {
                    const float* gp = (const float*)xb + (long)(rowB + m) * ldx + kk + g * 8;
                    const float4 u = *(const float4*)gp;
                    const float4 u2 = *(const float4*)(gp + 4);
                    h[0] = (_Float16)u.x;  h[1] = (_Float16)u.y;
                    h[2] = (_Float16)u.z;  h[3] = (_Float16)u.w;
                    h[4] = (_Float16)u2.x; h[5] = (_Float16)u2.y;
                    h[6] = (_Float16)u2.z; h[7] = (_Float16)u2.w;
                } else {
                    const uint4 v = *(const uint4*)((const u16*)xb + (long)(rowB + m) * ldx + kk + g * 8);
                    const u16* pv = (const u16*)&v;
#pragma unroll
                    for (int j = 0; j < 8; ++j) h[j] = (_Float16)bf2f(pv[j]);
                }
                *(f16x8*)&As[s * 8] = h;
            }
        } else {
            const u16* xs = (const u16*)xb;
            int kkr = kk;
            if (kk >= ksplit) { xs += ksecond; kkr -= ksplit; }
#pragma unroll
            for (int s = wid; s < WM * 8; s += 4)
                gload16(xs + (long)(rowB + s * 8 + rloc) * ldx + kkr + cg * 8,
                        &As[s * 512 + lane * 8]);
        }
        // ---- stage B tile ----
#pragma unroll
        for (int s = wid; s < WN * 8; s += 4)
            gload16(wtp + (long)(nBase + s * 8 + rloc) * K + kk + cg * 8,
                    &Bs[s * 512 + lane * 8]);
        __syncthreads();

        // ---- compute ----
        const int sel = (ROWW && kk >= ksplit) ? 1 : 0;
#pragma unroll
        for (int q = 0; q < 2; ++q) {
            f16x8 af[4], bfr[4];
#pragma unroll
            for (int mi = 0; mi < 4; ++mi) {
                const int mm = wm * 64 + mi * 16 + fm;
                af[mi] = *(const f16x8*)&As[mm * 64 + (((q * 4 + quad) ^ (mm & 7)) * 8)];
            }
            if constexpr (ROWW) {
#pragma unroll
                for (int mi = 0; mi < 4; ++mi) {
                    const _Float16 yh = ysc[sel][mi];
#pragma unroll
                    for (int j = 0; j < 8; ++j) af[mi][j] *= yh;
                }
            }
#pragma unroll
            for (int ni = 0; ni < 4; ++ni) {
                const int nn = wn * 64 + ni * 16 + fm;
                bfr[ni] = *(const f16x8*)&Bs[nn * 64 + (((q * 4 + quad) ^ (nn & 7)) * 8)];
            }
#pragma unroll
            for (int mi = 0; mi < 4; ++mi)
#pragma unroll
                for (int ni = 0; ni < 4; ++ni)
                    acc[mi][ni] = __builtin_amdgcn_mfma_f32_16x16x32_f16(
                        af[mi], bfr[ni], acc[mi][ni], 0, 0, 0);
        }
    }

    __syncthreads();

    // ---- epilogue ----
    float yv[16];
    if constexpr (ROWW) {
        const float* yp = Y0v + (long)inst * B_ROWS;
#pragma unroll
        for (int mi = 0; mi < 4; ++mi)
#pragma unroll
            for (int r = 0; r < 4; ++r)
                yv[mi * 4 + r] = yp[rowB + wm * 64 + mi * 16 + quad * 4 + r];
    }

#pragma unroll
    for (int ni = 0; ni < 4; ++ni) {
        const int nc = ni * 16 + fm;
        const int n = n0 + nc;
        float bS = 0.f, bP = 0.f, t0v = 0.f, t1v = 0.f;
        if constexpr (ROWW) {
            bP = biasP[(long)inst * bN + n];
            t0v = T0[(long)inst * bN + n];
            t1v = T1[(long)inst * bN + n];
        } else {
            bS = bsum[(long)inst * bN + n];
        }
        float s = 0.f, qq = 0.f;
#pragma unroll
        for (int mi = 0; mi < 4; ++mi) {
            const int rbase = rowB + wm * 64 + mi * 16 + quad * 4;
#pragma unroll
            for (int r = 0; r < 4; ++r) {
                float v;
                if constexpr (ROWW) {
                    const float y = yv[mi * 4 + r];
                    v = acc[mi][ni][r] + y * t0v + (1.f - y) * t1v + bP;
                } else {
                    v = acc[mi][ni][r] + bS;
                }
                v = fmaxf(v, 0.f);
                s += v; qq += v * v;
                op[(long)(rbase + r) * ldout + n] = f2h(v);
            }
        }
        s += __shfl_xor(s, 16);  s += __shfl_xor(s, 32);
        qq += __shfl_xor(qq, 16); qq += __shfl_xor(qq, 32);
        if (quad == 0) { redS[wid][nc] = s; redQ[wid][nc] = qq; }
    }
    __syncthreads();
    if (tid < WN * 64) {
        const int wnc = tid >> 6, within = tid & 63;
        float s = 0.f, q = 0.f;
#pragma unroll
        for (int w = 0; w < WM; ++w) {
            s += redS[w * WN + wnc][within];
            q += redQ[w * WN + wnc][within];
        }
        atomicAdd(&gsum[(long)inst * sstride + nBase + tid], s);
        atomicAdd(&gsq [(long)inst * sstride + nBase + tid], q);
    }
}

// ---------------------------------------------------------------------------
__global__ __launch_bounds__(256) void gate_kernel(
    const u16* __restrict__ zc,
    const float* __restrict__ stFs, const float* __restrict__ stFq,
    const float* __restrict__ g4, const float* __restrict__ be4,
    const float* __restrict__ Wy, const float* __restrict__ by,
    float* __restrict__ Y0)
{
    const int lane = threadIdx.x & 63;
    const int wid = threadIdx.x >> 6;
    const int k = blockIdx.y;
    const int row = blockIdx.x * 4 + wid;

    const float m = stFs[k * 64 + lane] * BINV;
    const float v = stFq[k * 64 + lane] * BINV - m * m;
    const float s = g4[lane] * rsqrtf(v + EPS_BN);
    const float t = be4[lane] - m * s;
    const float x = h2f(zc[((long)k * B_ROWS + row) * 64 + lane]) * s + t;

    float p0 = x * Wy[k * 128 + lane * 2 + 0];
    float p1 = x * Wy[k * 128 + lane * 2 + 1];
#pragma unroll
    for (int off = 32; off; off >>= 1) {
        p0 += __shfl_xor(p0, off);
        p1 += __shfl_xor(p1, off);
    }
    if (lane == 0) {
        const float l0 = p0 + by[k * 2 + 0];
        const float l1 = p1 + by[k * 2 + 1];
        Y0[(long)k * B_ROWS + row] = 1.f / (1.f + __expf(l1 - l0));
    }
}

// ---------------------------------------------------------------------------
__global__ __launch_bounds__(256) void heads_kernel(
    const u16* __restrict__ zxc,
    const float* __restrict__ stHs, const float* __restrict__ stHq,
    const float* __restrict__ g1, const float* __restrict__ be1,
    const float* __restrict__ Wo1, const float* __restrict__ bo1,
    const float* __restrict__ Wo2, const float* __restrict__ bo2,
    const float* __restrict__ Wo3, const float* __restrict__ bo3,
    const float* __restrict__ Wo4, const float* __restrict__ bo4,
    void* __restrict__ out, const int* __restrict__ dtflag)
{
    const int lane = threadIdx.x & 63;
    const int wid = threadIdx.x >> 6;
    const int k = blockIdx.y;
    const int row = blockIdx.x * 4 + wid;
    const int c0 = lane * 4;

    const ushort4 q = *(const ushort4*)(zxc + ((long)k * B_ROWS + row) * 256 + c0);
    float x[4] = {h2f(q.x), h2f(q.y), h2f(q.z), h2f(q.w)};
#pragma unroll
    for (int j = 0; j < 4; j++) {
        const int c = c0 + j;
        const float m = stHs[k * 256 + c] * BINV;
        const float v = stHq[k * 256 + c] * BINV - m * m;
        const float s = g1[c] * rsqrtf(v + EPS_BN);
        x[j] = x[j] * s + (be1[c] - m * s);
    }

    const float* Wo; const float* bo; int nk; long obase;
    if (k == 0)      { Wo = Wo1; bo = bo1; nk = 3; obase = 0; }
    else if (k == 1) { Wo = Wo2; bo = bo2; nk = 3; obase = (long)3 * B_ROWS; }
    else if (k == 2) { Wo = Wo3; bo = bo3; nk = 6; obase = (long)6 * B_ROWS; }
    else             { Wo = Wo4; bo = bo4; nk = 4; obase = (long)12 * B_ROWS; }

    float l[6];
#pragma unroll
    for (int j = 0; j < 6; j++) l[j] = 0.f;
#pragma unroll
    for (int j = 0; j < 6; j++) {
        if (j < nk) {
            float p = 0.f;
#pragma unroll
            for (int i = 0; i < 4; i++) p += x[i] * Wo[(c0 + i) * nk + j];
            l[j] = p;
        }
    }
#pragma unroll
    for (int off = 32; off; off >>= 1) {
#pragma unroll
        for (int j = 0; j < 6; j++) l[j] += __shfl_xor(l[j], off);
    }

    if (lane == 0) {
        float mx = -1e30f;
#pragma unroll
        for (int j = 0; j < 6; j++)
            if (j < nk) { l[j] += bo[j]; mx = fmaxf(mx, l[j]); }
        float e[6];
        float se = 0.f;
#pragma unroll
        for (int j = 0; j < 6; j++)
            if (j < nk) { e[j] = __expf(l[j] - mx); se += e[j]; }
        const float inv = 1.f / se;
        if (*dtflag) {
            u16* ob = (u16*)out;
#pragma unroll
            for (int j = 0; j < 6; j++)
                if (j < nk) ob[obase + (long)row * nk + j] = f2bf(e[j] * inv);
        } else {
            float* of = (float*)out;
#pragma unroll
            for (int j = 0; j < 6; j++)
                if (j < nk) of[obase + (long)row * nk + j] = e[j] * inv;
        }
    }
}

__global__ void fill_sentinel(u16* out, int n) {
    int i = blockIdx.x * 256 + threadIdx.x;
    if (i < n) out[i] = 0x3E80;
}

// ---------------------------------------------------------------------------
extern "C" void kernel_launch(void* const* d_in, const int* in_sizes, int n_in,
                              void* d_out, int out_size, void* d_ws, size_t ws_size,
                              hipStream_t stream)
{
    const long B = B_ROWS;
    char* ws = (char*)d_ws;
    const size_t MB = 1024 * 1024;

    // Lifetime-aliased activation layout (fp16)
    u16* z1  = (u16*)(ws);                      // [2][B][256]
    u16* z2  = (u16*)(ws + 32 * MB);            // [2][B][256]
    u16* za  = (u16*)(ws);                      // [4][B][128]
    u16* zbb = (u16*)(ws + 32 * MB);            // [4][B][64]
    u16* zc  = (u16*)(ws + 48 * MB);            // [4][B][64]
    u16* zxc = (u16*)(ws);                      // [4][B][256]
    u16* zb  = (u16*)(ws + 64 * MB);            // [k][s][B][256]
    float* Y0 = (float*)(ws + 192 * MB);                   // 512 KB
    float* stats = (float*)(ws + 192 * MB + 512 * 1024);   // 40 KB
    int* dtflag = (int*)(ws + 192 * MB + 576 * 1024);
    float* Pst = (float*)(ws + 192 * MB + 640 * 1024);     // small fp32 params

    // Wt region (fp16, prescaled+transposed weights)
    u16* WtA = (u16*)(ws + 193 * MB);                 // [256][512]
    u16* WtB = WtA + 131072;                          // [2][256][256]
    u16* WtC = WtB + 131072;                          // [8][256][256]
    u16* WtD = WtC + 524288;                          // [4][128][512]
    u16* WtH = WtD + 262144;                          // [4][256][512]
    u16* WtE = WtH + 524288;                          // [4][64][128]
    u16* WtF = WtE + 32768;                           // [4][64][64]
    float* biasArea = (float*)(ws + 197 * MB);
    float* bA = biasArea;        // 2048
    float* bB = bA + 2048;       // 2048
    float* bC = bB + 2048;       // 8192
    float* bD = bC + 8192;       // 2048
    float* bH = bD + 2048;       // 4096
    float* bE = bH + 4096;       // 1024
    float* bF = bE + 1024;       // 1024

    // fp32 param staging (gate/heads consumers)
    const int cIdx[20] = {6,7,10,11,12,13,20,21,22,23,24,25,28,29,30,31,32,33,34,35};
    PTab tab;
    int mapOff[36];
    int acc = 0;
    for (int i = 0; i < 20; i++) {
        tab.p[i] = d_in[cIdx[i]];
        tab.n[i] = in_sizes[cIdx[i]];
        tab.off[i] = acc;
        mapOff[cIdx[i]] = acc;
        acc += in_sizes[cIdx[i]];
    }
    const size_t need = 197 * MB + 20480 * 4 + 4096;
    if (need > ws_size || (size_t)acc * 4 > 384 * 1024) {
        fill_sentinel<<<(out_size + 255) / 256, 256, 0, stream>>>((u16*)d_out, out_size);
        return;
    }
    auto PF = [&](int idx) { return Pst + mapOff[idx]; };

    float* stAs = stats;        float* stAq = stAs + 512;   // [2][256]
    float* stBs = stAq + 512;   float* stBq = stBs + 512;   // [2][256]
    float* stCs = stBq + 512;   float* stCq = stCs + 2048;  // [k][s][256]
    float* stDs = stCq + 2048;  float* stDq = stDs + 512;   // [4][128]
    float* stEs = stDq + 512;   float* stEq = stEs + 256;   // [4][64]
    float* stFs = stEq + 256;   float* stFq = stFs + 256;   // [4][64]
    float* stHs = stFq + 256;   float* stHq = stHs + 1024;  // [4][256]

    hipMemsetAsync(stats, 0, 10240 * 4, stream);
    detect_dtype<<<1, 64, 0, stream>>>((const u16*)d_in[0], dtflag);
    convert_params<<<dim3(32, 20), 256, 0, stream>>>(tab, Pst, dtflag);

    const dim3 blk(256);
    const int BIGK = 1 << 29;  // "never split"

    // ---- Stage A: trunk L1 (dual-dtype X, VALU staging) ------------------
    prep_w<<<dim3(256, 2), blk, 0, stream>>>(
        d_in[2], 0, d_in[3], 0, nullptr, nullptr, 0, nullptr, nullptr, 0,
        dtflag, WtA, 0, bA, bA + 512, bA + 1024, bA + 1536, 256, 512, 512);
    gemm_mfma<true, false, 2, 2, 512><<<dim3(256, 2, 2), blk, 0, stream>>>(
        d_in[0], d_in[1], 0, 0, 512, BIGK, 0, dtflag, WtA, 0,
        bA, bA + 512, bA + 1024, bA + 1536, 256,
        z1, B * 256, 256, stAs, stAq, 256, nullptr);

    // ---- Stage B: trunk L2 (norm stA + g1/be1 folded into WtB) -----------
    prep_w<<<dim3(256, 2), blk, 0, stream>>>(
        d_in[4], 0, d_in[5], 0, stAs, stAq, 256, d_in[6], d_in[7], 255,
        dtflag, WtB, 65536, bB, bB + 512, bB + 1024, bB + 1536, 256, 256, 256);
    gemm_mfma<false, false, 2, 2, 256><<<dim3(256, 2, 2), blk, 0, stream>>>(
        z1, nullptr, B * 256, 3, 256, BIGK, 0, dtflag, WtB, 65536,
        bB, bB + 512, bB + 1024, bB + 1536, 256,
        z2, B * 256, 256, stBs, stBq, 256, nullptr);

    // ---- Stage C: 8 branch projections (norm stB + g2/be2) ---------------
    for (int s = 0; s < 2; s++) {
        prep_w<<<dim3(256, 4), blk, 0, stream>>>(
            d_in[s ? 16 : 14], 65536, d_in[s ? 17 : 15], 256,
            stBs + s * 256, stBq + s * 256, 0, d_in[8], d_in[9], 255,
            dtflag, WtC + s * 65536, 131072,
            bC + s * 256, bC + 2048 + s * 256, bC + 4096 + s * 256,
            bC + 6144 + s * 256, 512, 256, 256);
    }
    gemm_mfma<false, false, 2, 2, 256><<<dim3(256, 2, 8), blk, 0, stream>>>(
        z2, nullptr, B * 256, 1, 256, BIGK, 0, dtflag, WtC, 65536,
        bC, bC + 2048, bC + 4096, bC + 6144, 256,
        zb, B * 256, 256, stCs, stCq, 256, nullptr);

    // ---- Stage D prep+gemm, H prep (stC available) -----------------------
    prep_w<<<dim3(128, 4), blk, 0, stream>>>(
        d_in[18], 65536, d_in[19], 128, stCs, stCq, 512, d_in[6], d_in[7], 255,
        dtflag, WtD, 65536, bD, bD + 512, bD + 1024, bD + 1536, 128, 512, 512);
    prep_w<<<dim3(256, 4), blk, 0, stream>>>(
        d_in[26], 131072, d_in[27], 256, stCs, stCq, 512, d_in[6], d_in[7], 255,
        dtflag, WtH, 131072, bH, bH + 1024, bH + 2048, bH + 3072, 256, 512, 256);
    gemm_mfma<false, false, 2, 2, 512><<<dim3(256, 1, 4), blk, 0, stream>>>(
        zb, nullptr, 2 * B * 256, 3, 256, 256, B * 256, dtflag, WtD, 65536,
        bD, bD + 512, bD + 1024, bD + 1536, 128,
        za, B * 128, 128, stDs, stDq, 128, nullptr);

    // ---- Stage E: gating layer b (norm stD + g3/be3) ---------------------
    prep_w<<<dim3(64, 4), blk, 0, stream>>>(
        d_in[20], 8192, d_in[21], 64, stDs, stDq, 128, d_in[10], d_in[11], 127,
        dtflag, WtE, 8192, bE, bE + 256, bE + 512, bE + 768, 64, 128, 128);
    gemm_mfma<false, false, 4, 1, 128><<<dim3(128, 1, 4), blk, 0, stream>>>(
        za, nullptr, B * 128, 3, 128, BIGK, 0, dtflag, WtE, 8192,
        bE, bE + 256, bE + 512, bE + 768, 64,
        zbb, B * 64, 64, stEs, stEq, 64, nullptr);

    // ---- Stage F: gating layer c (norm stE + g4/be4) ---------------------
    prep_w<<<dim3(64, 4), blk, 0, stream>>>(
        d_in[22], 4096, d_in[23], 64, stEs, stEq, 64, d_in[12], d_in[13], 63,
        dtflag, WtF, 4096, bF, bF + 256, bF + 512, bF + 768, 64, 64, 64);
    gemm_mfma<false, false, 4, 1, 64><<<dim3(128, 1, 4), blk, 0, stream>>>(
        zbb, nullptr, B * 64, 3, 64, BIGK, 0, dtflag, WtF, 4096,
        bF, bF + 256, bF + 512, bF + 768, 64,
        zc, B * 64, 64, stFs, stFq, 64, nullptr);

    // ---- Gate ------------------------------------------------------------
    gate_kernel<<<dim3(B_ROWS / 4, 4), blk, 0, stream>>>(
        zc, stFs, stFq, PF(12), PF(13), PF(24), PF(25), Y0);

    // ---- Stage H: combine, gate weight folded into A-fragments -----------
    gemm_mfma<false, true, 2, 2, 512><<<dim3(256, 2, 4), blk, 0, stream>>>(
        zb, nullptr, 2 * B * 256, 3, 256, 256, B * 256, dtflag, WtH, 131072,
        bH, bH + 1024, bH + 2048, bH + 3072, 256,
        zxc, B * 256, 256, stHs, stHq, 256, Y0);

    // ---- Output heads ----------------------------------------------------
    heads_kernel<<<dim3(B_ROWS / 4, 4), blk, 0, stream>>>(
        zxc, stHs, stHq, PF(6), PF(7), PF(28), PF(29), PF(30), PF(31),
        PF(32), PF(33), PF(34), PF(35), d_out, dtflag);
}